// Round 5
// baseline (244.966 us; speedup 1.0000x reference)
//
#include <hip/hip_runtime.h>
#include <math.h>

// Problem constants (from reference)
#define NN 1024      // N
#define DD 64        // D
#define TT 2048      // T
#define UDEC 0.97f
#define EPS 1e-6f
// rho/a* chunking
#define CC 64        // chunk length along t
#define NCH 32       // TT/CC
// K3/K5 slicing: 16 slices of width 64
#define NSL 16
#define SLW 64
// X prefix-scan chunking: 128 chunks of 16
#define C2 16
#define NC2 128      // TT/C2
#define C2SH 4       // log2(C2)

struct KP {
    const float *E, *Dx, *Dy, *temb, *x0, *rho0;
    const int* toks;
    float *ys, *vs;
    float *Xp, *S, *Bb, *M, *Rho, *Gp, *Pp, *LNA, *DyT, *ET;
};

// True X[t][n] = Xp[t][n] + Bb[t>>C2SH][n].

// ---------------- K1: X intra-chunk prefix (blocks 0..511) + transposes (512..543) ----
__global__ __launch_bounds__(256) void k1_xscan(KP p) {
    __shared__ union { float Vs[C2][DD]; float T[64][65]; } sm;
    const int tid = threadIdx.x;
    const int bid = blockIdx.x;
    if (bid < 512) {
        const int cs = bid >> 2;                      // 0..127
        const int n  = (bid & 3) * 256 + tid;         // 0..1023
        for (int i = tid; i < C2 * DD; i += 256) {
            int s = i >> 6, d = i & 63;
            sm.Vs[s][d] = p.temb[p.toks[cs * C2 + s] * DD + d];
        }
        __syncthreads();
        float dxr[DD];
        const float4* dx4 = reinterpret_cast<const float4*>(p.Dx + n * DD);
#pragma unroll
        for (int j = 0; j < 16; ++j) {
            float4 v = dx4[j];
            dxr[4*j] = v.x; dxr[4*j+1] = v.y; dxr[4*j+2] = v.z; dxr[4*j+3] = v.w;
        }
        float run = 0.f;
#pragma unroll
        for (int s = 0; s < C2; ++s) {
            const float4* vr = reinterpret_cast<const float4*>(&sm.Vs[s][0]);  // broadcast
            float a0 = 0.f, a1 = 0.f, a2 = 0.f, a3 = 0.f;
#pragma unroll
            for (int j = 0; j < 16; ++j) {
                float4 v = vr[j];
                a0 += v.x * dxr[4*j];   a1 += v.y * dxr[4*j+1];
                a2 += v.z * dxr[4*j+2]; a3 += v.w * dxr[4*j+3];
            }
            run += fmaxf((a0 + a1) + (a2 + a3), 0.f);
            p.Xp[(cs * C2 + s) * NN + n] = run;
        }
        p.S[cs * NN + n] = run;
    } else if (bid < 528) {
        // Dy [1024][64] -> DyT [64][1024], tile of 64 n-rows
        const int n0 = (bid - 512) * 64;
#pragma unroll
        for (int k = 0; k < 16; ++k) {
            int e = k * 256 + tid;
            sm.T[e >> 6][e & 63] = p.Dy[n0 * DD + e];          // coalesced linear read
        }
        __syncthreads();
#pragma unroll
        for (int k = 0; k < 16; ++k) {
            int e = k * 256 + tid;
            int d = e >> 6, n_l = e & 63;
            p.DyT[d * NN + n0 + n_l] = sm.T[n_l][d];           // coalesced write
        }
    } else {
        // E [64][1024] -> ET [1024][64], tile of 64 n-cols
        const int n0 = (bid - 528) * 64;
#pragma unroll
        for (int k = 0; k < 16; ++k) {
            int e = k * 256 + tid;
            int d = e >> 6, n_l = e & 63;
            sm.T[d][n_l] = p.E[d * NN + n0 + n_l];             // coalesced read
        }
        __syncthreads();
#pragma unroll
        for (int k = 0; k < 16; ++k) {
            int e = k * 256 + tid;
            int n_l = e >> 6, d = e & 63;
            p.ET[(n0 + n_l) * DD + d] = sm.T[d][n_l];          // coalesced write
        }
    }
}

// ---------------- K2: serial scan of 128 chunk totals ----------------
__global__ __launch_bounds__(128) void k2_base(KP p) {
    const int n = blockIdx.x * 128 + threadIdx.x;
    float acc = p.x0[n];
#pragma unroll 16
    for (int cs = 0; cs < NC2; ++cs) {
        p.Bb[cs * NN + n] = acc;
        acc += p.S[cs * NN + n];
    }
}

// ---------------- K3: per-chunk rank collapse M_c[d][n] ----------------
__global__ __launch_bounds__(256) void k3_M(KP p) {
    __shared__ float Xs[CC][SLW + 1];
    __shared__ float Vw[CC][DD];
    __shared__ float pw[CC + 1];
    const int tid = threadIdx.x;
    const int c = blockIdx.x >> 4, q = blockIdx.x & 15;
    if (tid <= CC) pw[tid] = powf(UDEC, (float)tid);
    __syncthreads();
    for (int i = tid; i < CC * SLW; i += 256) {
        int s = i >> 6, n = i & 63;
        int t = c * CC + s, gn = q * SLW + n;
        Xs[s][n] = p.Xp[t * NN + gn] + p.Bb[(t >> C2SH) * NN + gn];
    }
    for (int i = tid; i < CC * DD; i += 256) {
        int s = i >> 6, d = i & 63;
        Vw[s][d] = p.temb[p.toks[c * CC + s] * DD + d] * pw[CC - s];
    }
    __syncthreads();
    const int n_l = tid & 63;
    const int dh  = tid >> 6;                     // 0..3 -> d = dh*16 + k
    float acc[16];
#pragma unroll
    for (int k = 0; k < 16; ++k) acc[k] = 0.f;
    for (int s = 0; s < CC; ++s) {
        float xv = Xs[s][n_l];
        const float4* vr = reinterpret_cast<const float4*>(&Vw[s][dh * 16]);
#pragma unroll
        for (int k4 = 0; k4 < 4; ++k4) {
            float4 v = vr[k4];
            acc[4*k4]   += v.x * xv;  acc[4*k4+1] += v.y * xv;
            acc[4*k4+2] += v.z * xv;  acc[4*k4+3] += v.w * xv;
        }
    }
#pragma unroll
    for (int k = 0; k < 16; ++k)
        p.M[(c * DD + dh * 16 + k) * NN + q * SLW + n_l] = acc[k];
}

// ---------------- K4: elementwise chunk scan Rho[c] ----------------
__global__ __launch_bounds__(256) void k4_rho(KP p) {
    const int el = blockIdx.x * 256 + threadIdx.x;
    const float uc = powf(UDEC, (float)CC);
    float acc = p.rho0[el];
#pragma unroll
    for (int c = 0; c < NCH; ++c) {
        p.Rho[c * (DD * NN) + el] = acc;
        acc = fmaf(acc, uc, p.M[c * (DD * NN) + el]);
    }
}

// ---------------- K5: partial Gram Gp + inter Pp ----------------
__global__ __launch_bounds__(256) void k5_gram(KP p) {
    __shared__ float Xs[CC][SLW + 1];
    __shared__ float Rs[CC][SLW + 1];
    const int tid = threadIdx.x;
    const int c = blockIdx.x >> 4, q = blockIdx.x & 15;
    for (int i = tid; i < CC * SLW; i += 256) {
        int s = i >> 6, n = i & 63;
        int t = c * CC + s, gn = q * SLW + n;
        Xs[s][n] = p.Xp[t * NN + gn] + p.Bb[(t >> C2SH) * NN + gn];
        Rs[s][n] = p.Rho[(c * DD + s) * NN + gn];   // DD==CC rows
    }
    __syncthreads();
    const int ti = tid >> 4;   // t = ti*4+a
    const int sj = tid & 15;   // s/d = sj*4+b
    float accG[16], accP[16];
#pragma unroll
    for (int k = 0; k < 16; ++k) { accG[k] = 0.f; accP[k] = 0.f; }
    for (int n = 0; n < SLW; ++n) {
        float xt[4], xs[4], rv[4];
#pragma unroll
        for (int a = 0; a < 4; ++a) xt[a] = Xs[ti * 4 + a][n];
#pragma unroll
        for (int b = 0; b < 4; ++b) { xs[b] = Xs[sj * 4 + b][n]; rv[b] = Rs[sj * 4 + b][n]; }
#pragma unroll
        for (int a = 0; a < 4; ++a)
#pragma unroll
            for (int b = 0; b < 4; ++b) {
                accG[a * 4 + b] += xt[a] * xs[b];
                accP[a * 4 + b] += xt[a] * rv[b];
            }
    }
    float* gbase = p.Gp + ((size_t)(c * NSL + q) * CC) * CC;
    float* pbase = p.Pp + ((size_t)(c * NSL + q) * CC) * DD;
#pragma unroll
    for (int a = 0; a < 4; ++a) {
        *reinterpret_cast<float4*>(gbase + (ti * 4 + a) * CC + sj * 4) =
            make_float4(accG[a*4], accG[a*4+1], accG[a*4+2], accG[a*4+3]);
        *reinterpret_cast<float4*>(pbase + (ti * 4 + a) * DD + sj * 4) =
            make_float4(accP[a*4], accP[a*4+1], accP[a*4+2], accP[a*4+3]);
    }
}

// ---------------- K6: slice-reduce + decay-weighted a* + LN(ddof=1) ----------------
// grid 512 (32 chunks x 16 groups of 4 rows), block 256; lane = d, wave = row.
__global__ __launch_bounds__(256) void k6_astar(KP p) {
    __shared__ float Gs[4][CC];
    __shared__ float Ps[4][DD];
    __shared__ float Ve[CC][DD];
    __shared__ float pw[CC + 1];
    const int tid = threadIdx.x;
    const int c = blockIdx.x >> 4, rg = blockIdx.x & 15;  // rows rg*4..rg*4+3
    if (tid <= CC) pw[tid] = powf(UDEC, (float)tid);
    {
        int r = tid >> 6, s2 = tid & 63;
        int t = rg * 4 + r;
        float ag = 0.f, ap = 0.f;
#pragma unroll
        for (int qq = 0; qq < NSL; ++qq) {
            ag += p.Gp[((size_t)(c * NSL + qq) * CC + t) * CC + s2];
            ap += p.Pp[((size_t)(c * NSL + qq) * CC + t) * DD + s2];
        }
        Gs[r][s2] = ag;
        Ps[r][s2] = ap;
    }
    for (int i = tid; i < CC * DD; i += 256) {
        int s2 = i >> 6, d = i & 63;
        Ve[s2][d] = p.temb[p.toks[c * CC + s2] * DD + d];
    }
    __syncthreads();
    const int r = tid >> 6, d = tid & 63;
    const int t_l = rg * 4 + r;
    float a = pw[t_l] * Ps[r][d];
    for (int s2 = 0; s2 < t_l; ++s2) {
        float w = pw[t_l - s2] * Gs[r][s2];      // wave-uniform
        a += w * Ve[s2][d];                       // lanes contiguous d
    }
    // LN across the 64 lanes (d) of this row
    float s = a;
#pragma unroll
    for (int m = 32; m >= 1; m >>= 1) s += __shfl_xor(s, m, 64);
    float mean = s * (1.f / DD);
    float z = a - mean;
    float v2 = z * z;
#pragma unroll
    for (int m = 32; m >= 1; m >>= 1) v2 += __shfl_xor(v2, m, 64);
    float inv = 1.f / (sqrtf(v2 * (1.f / (DD - 1))) + EPS);
    p.LNA[(c * CC + t_l) * DD + d] = z * inv;
}

// ---------------- K7: y = relu(LNA@DyT)*relu(x); v = LN(ys@ET) ----------------
// grid 512 (4 t-rows per block), block 256. All global accesses lane-contiguous.
__global__ __launch_bounds__(256) void k7_yv(KP p) {
    __shared__ float Lsh[4][DD];
    __shared__ float ys4[NN][4];     // packed y rows for phase B b128 broadcast
    __shared__ float part[16][128];  // A: [2 dh][4 r][128 n]; B: [4 nq][4 r][64 d]
    const int tid = threadIdx.x;
    const int t0 = blockIdx.x * 4;
    Lsh[tid >> 6][tid & 63] = p.LNA[t0 * DD + tid];
    __syncthreads();
    // ---- phase A: y[4][1024] = L[4][64] @ DyT[64][1024], split d into halves ----
    const int dh = tid >> 7;         // 0/1 -> d-range dh*32..+32
    const int n2 = tid & 127;
    float Lr[4 * 32];                // register fragment of L
#pragma unroll
    for (int r = 0; r < 4; ++r)
#pragma unroll
        for (int k = 0; k < 8; ++k) {
            float4 v = *reinterpret_cast<const float4*>(&Lsh[r][dh * 32 + 4 * k]);
            Lr[r*32 + 4*k]   = v.x; Lr[r*32 + 4*k+1] = v.y;
            Lr[r*32 + 4*k+2] = v.z; Lr[r*32 + 4*k+3] = v.w;
        }
    for (int tile = 0; tile < 8; ++tile) {
        const int n0 = tile * 128;
        float acc0 = 0.f, acc1 = 0.f, acc2 = 0.f, acc3 = 0.f;
        const float* dptr = p.DyT + (size_t)(dh * 32) * NN + n0 + n2;
#pragma unroll
        for (int d = 0; d < 32; ++d) {
            float v = dptr[(size_t)d * NN];       // coalesced over n2
            acc0 += Lr[d] * v;        acc1 += Lr[32 + d] * v;
            acc2 += Lr[64 + d] * v;   acc3 += Lr[96 + d] * v;
        }
        part[dh * 4 + 0][n2] = acc0;
        part[dh * 4 + 1][n2] = acc1;
        part[dh * 4 + 2][n2] = acc2;
        part[dh * 4 + 3][n2] = acc3;
        __syncthreads();
#pragma unroll
        for (int half = 0; half < 2; ++half) {
            int out = half * 256 + tid;
            int r = out >> 7, nn = out & 127;
            float yc = part[r][nn] + part[4 + r][nn];
            int t = t0 + r, n = n0 + nn;
            float xv = p.Xp[t * NN + n] + p.Bb[(t >> C2SH) * NN + n];
            float yv = fmaxf(yc, 0.f) * fmaxf(xv, 0.f);
            p.ys[t * NN + n] = yv;                // coalesced
            ys4[n][r] = yv;
        }
        __syncthreads();
    }
    // ---- phase B: pre[4][64] = ys[4][1024] @ ET[1024][64], split n into quarters ----
    const int d  = tid & 63;
    const int nq = tid >> 6;
    float b0 = 0.f, b1 = 0.f, b2 = 0.f, b3 = 0.f;
    const float* eptr = p.ET + (size_t)(nq * 256) * DD + d;
#pragma unroll 8
    for (int i = 0; i < 256; ++i) {
        float ev = eptr[(size_t)i * DD];          // coalesced over d
        float4 yv = *reinterpret_cast<const float4*>(&ys4[nq * 256 + i][0]);  // broadcast
        b0 += ev * yv.x; b1 += ev * yv.y; b2 += ev * yv.z; b3 += ev * yv.w;
    }
    part[nq * 4 + 0][d] = b0;
    part[nq * 4 + 1][d] = b1;
    part[nq * 4 + 2][d] = b2;
    part[nq * 4 + 3][d] = b3;
    __syncthreads();
    const int r = tid >> 6;
    float pre = part[r][d] + part[4 + r][d] + part[8 + r][d] + part[12 + r][d];
    // LN across the 64 lanes (d) of row r
    float s = pre;
#pragma unroll
    for (int m = 32; m >= 1; m >>= 1) s += __shfl_xor(s, m, 64);
    float mean = s * (1.f / DD);
    float z = pre - mean;
    float v2 = z * z;
#pragma unroll
    for (int m = 32; m >= 1; m >>= 1) v2 += __shfl_xor(v2, m, 64);
    float inv = 1.f / (sqrtf(v2 * (1.f / (DD - 1))) + EPS);
    p.vs[(t0 + r) * DD + d] = z * inv;
}

// ---------------------------------------------------------------------------
extern "C" void kernel_launch(void* const* d_in, const int* in_sizes, int n_in,
                              void* d_out, int out_size, void* d_ws, size_t ws_size,
                              hipStream_t stream) {
    (void)in_sizes; (void)n_in; (void)out_size; (void)ws_size;
    KP p;
    p.E    = (const float*)d_in[0];   // [D,N]
    p.Dx   = (const float*)d_in[1];   // [N,D]
    p.Dy   = (const float*)d_in[2];   // [N,D]
    p.temb = (const float*)d_in[3];   // [V,D]
    p.x0   = (const float*)d_in[4];   // [N]
    p.rho0 = (const float*)d_in[5];   // [D,N]
    p.toks = (const int*)d_in[6];     // [T]

    p.ys = (float*)d_out;                    // [T,N]
    p.vs = p.ys + (size_t)TT * NN;           // [T,D]

    float* w = (float*)d_ws;                 // ~43 MiB used
    p.Xp  = w;                                       // TT*NN
    p.S   = p.Xp  + (size_t)TT * NN;                 // NC2*NN
    p.Bb  = p.S   + (size_t)NC2 * NN;                // NC2*NN
    p.M   = p.Bb  + (size_t)NC2 * NN;                // NCH*DD*NN
    p.Rho = p.M   + (size_t)NCH * DD * NN;           // NCH*DD*NN
    p.Gp  = p.Rho + (size_t)NCH * DD * NN;           // NCH*NSL*CC*CC
    p.Pp  = p.Gp  + (size_t)NCH * NSL * CC * CC;     // NCH*NSL*CC*DD
    p.LNA = p.Pp  + (size_t)NCH * NSL * CC * DD;     // TT*DD
    p.DyT = p.LNA + (size_t)TT * DD;                 // DD*NN
    p.ET  = p.DyT + (size_t)DD * NN;                 // NN*DD

    k1_xscan<<<dim3(544), 256, 0, stream>>>(p);
    k2_base <<<dim3(8),   128, 0, stream>>>(p);
    k3_M    <<<dim3(512), 256, 0, stream>>>(p);
    k4_rho  <<<dim3(256), 256, 0, stream>>>(p);
    k5_gram <<<dim3(512), 256, 0, stream>>>(p);
    k6_astar<<<dim3(512), 256, 0, stream>>>(p);
    k7_yv   <<<dim3(512), 256, 0, stream>>>(p);
}

// Round 6
// 220.816 us; speedup vs baseline: 1.1094x; 1.1094x over previous
//
#include <hip/hip_runtime.h>
#include <math.h>

// Problem constants (from reference)
#define NN 1024      // N
#define DD 64        // D
#define TT 2048      // T
#define UDEC 0.97f
#define EPS 1e-6f
// rho/a* chunking
#define CC 64        // chunk length along t
#define NCH 32       // TT/CC
// K3 slicing: 16 slices of width 64 (block 512)
#define NS3 16
#define SL3 64
// K5 slicing: 32 slices of width 32 (grid 1024)
#define NS5 32
#define SL5 32
// X prefix-scan chunking: 256 chunks of 8
#define C2 8
#define NC2 256      // TT/C2
#define C2SH 3       // log2(C2)

struct KP {
    const float *E, *Dx, *Dy, *temb, *x0, *rho0;
    const int* toks;
    float *ys, *vs;
    float *Xp, *S, *Bb, *M, *Rho, *Gp, *Pp, *LNA, *DyT, *ET;
};

// True X[t][n] = Xp[t][n] + Bb[t>>C2SH][n].

// ---------------- K1: X intra-chunk prefix (blocks 0..1023) + transposes (1024..1055) ----
__global__ __launch_bounds__(256) void k1_xscan(KP p) {
    __shared__ union { float Vs[C2][DD]; float T[64][65]; } sm;
    const int tid = threadIdx.x;
    const int bid = blockIdx.x;
    if (bid < 1024) {
        const int cs = bid >> 2;                      // 0..255
        const int n  = (bid & 3) * 256 + tid;         // 0..1023
        for (int i = tid; i < C2 * DD; i += 256) {
            int s = i >> 6, d = i & 63;
            sm.Vs[s][d] = p.temb[p.toks[cs * C2 + s] * DD + d];
        }
        __syncthreads();
        float dxr[DD];
        const float4* dx4 = reinterpret_cast<const float4*>(p.Dx + n * DD);
#pragma unroll
        for (int j = 0; j < 16; ++j) {
            float4 v = dx4[j];
            dxr[4*j] = v.x; dxr[4*j+1] = v.y; dxr[4*j+2] = v.z; dxr[4*j+3] = v.w;
        }
        float run = 0.f;
#pragma unroll
        for (int s = 0; s < C2; ++s) {
            const float4* vr = reinterpret_cast<const float4*>(&sm.Vs[s][0]);  // broadcast
            float a0 = 0.f, a1 = 0.f, a2 = 0.f, a3 = 0.f;
#pragma unroll
            for (int j = 0; j < 16; ++j) {
                float4 v = vr[j];
                a0 += v.x * dxr[4*j];   a1 += v.y * dxr[4*j+1];
                a2 += v.z * dxr[4*j+2]; a3 += v.w * dxr[4*j+3];
            }
            run += fmaxf((a0 + a1) + (a2 + a3), 0.f);
            p.Xp[(cs * C2 + s) * NN + n] = run;
        }
        p.S[cs * NN + n] = run;
    } else if (bid < 1040) {
        // Dy [1024][64] -> DyT [64][1024], tile of 64 n-rows
        const int n0 = (bid - 1024) * 64;
#pragma unroll
        for (int k = 0; k < 16; ++k) {
            int e = k * 256 + tid;
            sm.T[e >> 6][e & 63] = p.Dy[n0 * DD + e];          // coalesced linear read
        }
        __syncthreads();
#pragma unroll
        for (int k = 0; k < 16; ++k) {
            int e = k * 256 + tid;
            int d = e >> 6, n_l = e & 63;
            p.DyT[d * NN + n0 + n_l] = sm.T[n_l][d];           // coalesced write
        }
    } else {
        // E [64][1024] -> ET [1024][64], tile of 64 n-cols
        const int n0 = (bid - 1040) * 64;
#pragma unroll
        for (int k = 0; k < 16; ++k) {
            int e = k * 256 + tid;
            int d = e >> 6, n_l = e & 63;
            sm.T[d][n_l] = p.E[d * NN + n0 + n_l];             // coalesced read
        }
        __syncthreads();
#pragma unroll
        for (int k = 0; k < 16; ++k) {
            int e = k * 256 + tid;
            int n_l = e >> 6, d = e & 63;
            p.ET[(n0 + n_l) * DD + d] = sm.T[d][n_l];          // coalesced write
        }
    }
}

// ---------------- K2: serial scan of 256 chunk totals ----------------
__global__ __launch_bounds__(256) void k2_base(KP p) {
    const int n = blockIdx.x * 256 + threadIdx.x;   // grid 4
    float acc = p.x0[n];
#pragma unroll 8
    for (int cs = 0; cs < NC2; ++cs) {
        p.Bb[cs * NN + n] = acc;
        acc += p.S[cs * NN + n];
    }
}

// ---------------- K3: per-chunk rank collapse M_c[d][n] ----------------
// grid 512 (32 chunks x 16 slices of 64), block 512 -> 16 waves/CU.
__global__ __launch_bounds__(512) void k3_M(KP p) {
    __shared__ float Xs[CC][SL3 + 1];
    __shared__ float Vw[CC][DD];
    __shared__ float pw[CC + 1];
    const int tid = threadIdx.x;
    const int c = blockIdx.x >> 4, q = blockIdx.x & 15;
    if (tid <= CC) pw[tid] = powf(UDEC, (float)tid);
    __syncthreads();
    for (int i = tid; i < CC * SL3; i += 512) {
        int s = i >> 6, n = i & 63;
        int t = c * CC + s, gn = q * SL3 + n;
        Xs[s][n] = p.Xp[t * NN + gn] + p.Bb[(t >> C2SH) * NN + gn];
    }
    for (int i = tid; i < CC * DD; i += 512) {
        int s = i >> 6, d = i & 63;
        Vw[s][d] = p.temb[p.toks[c * CC + s] * DD + d] * pw[CC - s];
    }
    __syncthreads();
    const int n_l = tid & 63;
    const int dh  = tid >> 6;                     // 0..7 (wave-uniform) -> d = dh*8 + k
    float acc[8];
#pragma unroll
    for (int k = 0; k < 8; ++k) acc[k] = 0.f;
    for (int s = 0; s < CC; ++s) {
        float xv = Xs[s][n_l];
        const float4* vr = reinterpret_cast<const float4*>(&Vw[s][dh * 8]);  // wave broadcast
#pragma unroll
        for (int k4 = 0; k4 < 2; ++k4) {
            float4 v = vr[k4];
            acc[4*k4]   += v.x * xv;  acc[4*k4+1] += v.y * xv;
            acc[4*k4+2] += v.z * xv;  acc[4*k4+3] += v.w * xv;
        }
    }
#pragma unroll
    for (int k = 0; k < 8; ++k)
        p.M[(c * DD + dh * 8 + k) * NN + q * SL3 + n_l] = acc[k];
}

// ---------------- K4: elementwise chunk scan Rho[c] ----------------
__global__ __launch_bounds__(256) void k4_rho(KP p) {
    const int el = blockIdx.x * 256 + threadIdx.x;
    const float uc = powf(UDEC, (float)CC);
    float acc = p.rho0[el];
#pragma unroll
    for (int c = 0; c < NCH; ++c) {
        p.Rho[c * (DD * NN) + el] = acc;
        acc = fmaf(acc, uc, p.M[c * (DD * NN) + el]);
    }
}

// ---------------- K5: partial Gram Gp + inter Pp ----------------
// grid 1024 (32 chunks x 32 slices of 32), block 256 -> 4 blocks/CU.
__global__ __launch_bounds__(256) void k5_gram(KP p) {
    __shared__ float Xs[CC][SL5 + 1];
    __shared__ float Rs[CC][SL5 + 1];
    const int tid = threadIdx.x;
    const int c = blockIdx.x >> 5, q = blockIdx.x & 31;
    for (int i = tid; i < CC * SL5; i += 256) {
        int s = i >> 5, n = i & 31;
        int t = c * CC + s, gn = q * SL5 + n;
        Xs[s][n] = p.Xp[t * NN + gn] + p.Bb[(t >> C2SH) * NN + gn];
        Rs[s][n] = p.Rho[(c * DD + s) * NN + gn];   // DD==CC rows
    }
    __syncthreads();
    const int ti = tid >> 4;   // t = ti*4+a
    const int sj = tid & 15;   // s/d = sj*4+b
    float accG[16], accP[16];
#pragma unroll
    for (int k = 0; k < 16; ++k) { accG[k] = 0.f; accP[k] = 0.f; }
    for (int n = 0; n < SL5; ++n) {
        float xt[4], xs[4], rv[4];
#pragma unroll
        for (int a = 0; a < 4; ++a) xt[a] = Xs[ti * 4 + a][n];
#pragma unroll
        for (int b = 0; b < 4; ++b) { xs[b] = Xs[sj * 4 + b][n]; rv[b] = Rs[sj * 4 + b][n]; }
#pragma unroll
        for (int a = 0; a < 4; ++a)
#pragma unroll
            for (int b = 0; b < 4; ++b) {
                accG[a * 4 + b] += xt[a] * xs[b];
                accP[a * 4 + b] += xt[a] * rv[b];
            }
    }
    float* gbase = p.Gp + ((size_t)(c * NS5 + q) * CC) * CC;
    float* pbase = p.Pp + ((size_t)(c * NS5 + q) * CC) * DD;
#pragma unroll
    for (int a = 0; a < 4; ++a) {
        *reinterpret_cast<float4*>(gbase + (ti * 4 + a) * CC + sj * 4) =
            make_float4(accG[a*4], accG[a*4+1], accG[a*4+2], accG[a*4+3]);
        *reinterpret_cast<float4*>(pbase + (ti * 4 + a) * DD + sj * 4) =
            make_float4(accP[a*4], accP[a*4+1], accP[a*4+2], accP[a*4+3]);
    }
}

// ---------------- K6: slice-reduce + decay-weighted a* + LN(ddof=1) ----------------
// grid 512 (32 chunks x 16 groups of 4 rows), block 256; lane = d, wave = row.
__global__ __launch_bounds__(256) void k6_astar(KP p) {
    __shared__ float Gs[4][CC];
    __shared__ float Ps[4][DD];
    __shared__ float Ve[CC][DD];
    __shared__ float pw[CC + 1];
    const int tid = threadIdx.x;
    const int c = blockIdx.x >> 4, rg = blockIdx.x & 15;  // rows rg*4..rg*4+3
    if (tid <= CC) pw[tid] = powf(UDEC, (float)tid);
    {
        int r = tid >> 6, s2 = tid & 63;
        int t = rg * 4 + r;
        float ag = 0.f, ap = 0.f;
#pragma unroll
        for (int qq = 0; qq < NS5; ++qq) {
            ag += p.Gp[((size_t)(c * NS5 + qq) * CC + t) * CC + s2];
            ap += p.Pp[((size_t)(c * NS5 + qq) * CC + t) * DD + s2];
        }
        Gs[r][s2] = ag;
        Ps[r][s2] = ap;
    }
    for (int i = tid; i < CC * DD; i += 256) {
        int s2 = i >> 6, d = i & 63;
        Ve[s2][d] = p.temb[p.toks[c * CC + s2] * DD + d];
    }
    __syncthreads();
    const int r = tid >> 6, d = tid & 63;
    const int t_l = rg * 4 + r;
    float a = pw[t_l] * Ps[r][d];
    for (int s2 = 0; s2 < t_l; ++s2) {
        float w = pw[t_l - s2] * Gs[r][s2];      // wave-uniform
        a += w * Ve[s2][d];                       // lanes contiguous d
    }
    // LN across the 64 lanes (d) of this row
    float s = a;
#pragma unroll
    for (int m = 32; m >= 1; m >>= 1) s += __shfl_xor(s, m, 64);
    float mean = s * (1.f / DD);
    float z = a - mean;
    float v2 = z * z;
#pragma unroll
    for (int m = 32; m >= 1; m >>= 1) v2 += __shfl_xor(v2, m, 64);
    float inv = 1.f / (sqrtf(v2 * (1.f / (DD - 1))) + EPS);
    p.LNA[(c * CC + t_l) * DD + d] = z * inv;
}

// ---------------- K7a: y = relu(LNA@DyT)*relu(x) ----------------
// grid 1024 (512 t-groups of 4 x 2 n-halves of 512), block 256 -> 4 blocks/CU.
__global__ __launch_bounds__(256) void k7a_y(KP p) {
    __shared__ float Lsh[4][DD];
    __shared__ float part[8][128];   // [2 dh][4 r][128 n]
    const int tid = threadIdx.x;
    const int t0 = (blockIdx.x >> 1) * 4;
    const int nb = (blockIdx.x & 1) * 512;
    Lsh[tid >> 6][tid & 63] = p.LNA[t0 * DD + tid];
    __syncthreads();
    const int dh = tid >> 7;         // 0/1 -> d-range dh*32..+32
    const int n2 = tid & 127;
    float Lr[4 * 32];                // register fragment of L
#pragma unroll
    for (int r = 0; r < 4; ++r)
#pragma unroll
        for (int k = 0; k < 8; ++k) {
            float4 v = *reinterpret_cast<const float4*>(&Lsh[r][dh * 32 + 4 * k]);
            Lr[r*32 + 4*k]   = v.x; Lr[r*32 + 4*k+1] = v.y;
            Lr[r*32 + 4*k+2] = v.z; Lr[r*32 + 4*k+3] = v.w;
        }
    for (int tile = 0; tile < 4; ++tile) {
        const int n0 = nb + tile * 128;
        float acc0 = 0.f, acc1 = 0.f, acc2 = 0.f, acc3 = 0.f;
        const float* dptr = p.DyT + (size_t)(dh * 32) * NN + n0 + n2;
#pragma unroll
        for (int d = 0; d < 32; ++d) {
            float v = dptr[(size_t)d * NN];       // coalesced over n2
            acc0 += Lr[d] * v;        acc1 += Lr[32 + d] * v;
            acc2 += Lr[64 + d] * v;   acc3 += Lr[96 + d] * v;
        }
        part[dh * 4 + 0][n2] = acc0;
        part[dh * 4 + 1][n2] = acc1;
        part[dh * 4 + 2][n2] = acc2;
        part[dh * 4 + 3][n2] = acc3;
        __syncthreads();
#pragma unroll
        for (int half = 0; half < 2; ++half) {
            int out = half * 256 + tid;
            int r = out >> 7, nn = out & 127;
            float yc = part[r][nn] + part[4 + r][nn];
            int t = t0 + r, n = n0 + nn;
            float xv = p.Xp[t * NN + n] + p.Bb[(t >> C2SH) * NN + n];
            p.ys[t * NN + n] = fmaxf(yc, 0.f) * fmaxf(xv, 0.f);   // coalesced
        }
        __syncthreads();
    }
}

// ---------------- K7b: v = LN(ys@ET), ddof=1 ----------------
// grid 512 (4 t-rows each), block 512 -> 2 blocks/CU, 16 waves/CU.
__global__ __launch_bounds__(512) void k7b_v(KP p) {
    __shared__ float ys4[NN][4];       // 16 KB, packed for b128 broadcast
    __shared__ float part[8][4 * 65];  // 8 n-groups x 4 rows x 64 d (+pad)
    const int tid = threadIdx.x;
    const int t0 = blockIdx.x * 4;
    for (int i = tid; i < 4 * NN; i += 512) {
        int r = i >> 10, n = i & 1023;
        ys4[n][r] = p.ys[(t0 + r) * NN + n];       // coalesced read
    }
    __syncthreads();
    const int d  = tid & 63;
    const int nq = tid >> 6;           // 0..7, wave-uniform
    float b0 = 0.f, b1 = 0.f, b2 = 0.f, b3 = 0.f;
    const float* eptr = p.ET + (size_t)(nq * 128) * DD + d;
#pragma unroll 8
    for (int i = 0; i < 128; ++i) {
        float ev = eptr[(size_t)i * DD];           // coalesced over d
        float4 yv = *reinterpret_cast<const float4*>(&ys4[nq * 128 + i][0]);  // broadcast
        b0 += ev * yv.x; b1 += ev * yv.y; b2 += ev * yv.z; b3 += ev * yv.w;
    }
    part[nq][0 * 65 + d] = b0;
    part[nq][1 * 65 + d] = b1;
    part[nq][2 * 65 + d] = b2;
    part[nq][3 * 65 + d] = b3;
    __syncthreads();
    if (tid < 256) {
        const int r = tid >> 6;        // wave-uniform
        float pre = 0.f;
#pragma unroll
        for (int qq = 0; qq < 8; ++qq) pre += part[qq][r * 65 + d];
        // LN across the 64 lanes (d) of row r
        float s = pre;
#pragma unroll
        for (int m = 32; m >= 1; m >>= 1) s += __shfl_xor(s, m, 64);
        float mean = s * (1.f / DD);
        float z = pre - mean;
        float v2 = z * z;
#pragma unroll
        for (int m = 32; m >= 1; m >>= 1) v2 += __shfl_xor(v2, m, 64);
        float inv = 1.f / (sqrtf(v2 * (1.f / (DD - 1))) + EPS);
        p.vs[(t0 + r) * DD + d] = z * inv;
    }
}

// ---------------------------------------------------------------------------
extern "C" void kernel_launch(void* const* d_in, const int* in_sizes, int n_in,
                              void* d_out, int out_size, void* d_ws, size_t ws_size,
                              hipStream_t stream) {
    (void)in_sizes; (void)n_in; (void)out_size; (void)ws_size;
    KP p;
    p.E    = (const float*)d_in[0];   // [D,N]
    p.Dx   = (const float*)d_in[1];   // [N,D]
    p.Dy   = (const float*)d_in[2];   // [N,D]
    p.temb = (const float*)d_in[3];   // [V,D]
    p.x0   = (const float*)d_in[4];   // [N]
    p.rho0 = (const float*)d_in[5];   // [D,N]
    p.toks = (const int*)d_in[6];     // [T]

    p.ys = (float*)d_out;                    // [T,N]
    p.vs = p.ys + (size_t)TT * NN;           // [T,D]

    float* w = (float*)d_ws;                 // ~59 MiB used
    p.Xp  = w;                                       // TT*NN
    p.S   = p.Xp  + (size_t)TT * NN;                 // NC2*NN
    p.Bb  = p.S   + (size_t)NC2 * NN;                // NC2*NN
    p.M   = p.Bb  + (size_t)NC2 * NN;                // NCH*DD*NN
    p.Rho = p.M   + (size_t)NCH * DD * NN;           // NCH*DD*NN
    p.Gp  = p.Rho + (size_t)NCH * DD * NN;           // NCH*NS5*CC*CC
    p.Pp  = p.Gp  + (size_t)NCH * NS5 * CC * CC;     // NCH*NS5*CC*DD
    p.LNA = p.Pp  + (size_t)NCH * NS5 * CC * DD;     // TT*DD
    p.DyT = p.LNA + (size_t)TT * DD;                 // DD*NN
    p.ET  = p.DyT + (size_t)DD * NN;                 // NN*DD

    k1_xscan<<<dim3(1056), 256, 0, stream>>>(p);
    k2_base <<<dim3(4),    256, 0, stream>>>(p);
    k3_M    <<<dim3(512),  512, 0, stream>>>(p);
    k4_rho  <<<dim3(256),  256, 0, stream>>>(p);
    k5_gram <<<dim3(1024), 256, 0, stream>>>(p);
    k6_astar<<<dim3(512),  256, 0, stream>>>(p);
    k7a_y   <<<dim3(1024), 256, 0, stream>>>(p);
    k7b_v   <<<dim3(512),  512, 0, stream>>>(p);
}